// Round 12
// baseline (145.304 us; speedup 1.0000x reference)
//
#include <hip/hip_runtime.h>
#include <math.h>

// Problem: B=8, T=8192, D=128, E=8, I=16.  BT = 65536 tokens.
// Outputs concatenated f32: out0 [BT,128] | out1 [BT,8] | out2 [BT,8,128]
// R12: R9 (78.4 us) with stage-B software-pipelined into P4: expert e's y
// (4 MFMA + 4 erff) computed right before its P4 use (wave-private LDS,
// fence-only), overlapping y-compute with the out2 store stream. w2 B-frags
// read directly from the d_ws image (L1/L2-hot) -> w2t LDS staging + bar2/3
// deleted. 66KB LDS, (256,2), xv kept -- R9-verbatim elsewhere.
#define O1_OFF 8388608
#define O2_OFF 8912896

// d_ws layout: [0,32768) w1t image | [32768,65536) w2t image | [65536,69632) gfr image
#define WS_W2T 32768
#define WS_GFR 65536

typedef __attribute__((ext_vector_type(8))) short short8;
typedef __attribute__((ext_vector_type(4))) float f32x4;

static __device__ __forceinline__ unsigned short f2bf(float f) {
    unsigned u = __builtin_bit_cast(unsigned, f);
    u = (u + 0x7fffu + ((u >> 16) & 1u)) >> 16;   // RNE
    return (unsigned short)u;
}

// swizzled byte offset inside a [rows][16 x 16B-chunks] LDS region (weights/xn/y)
static __device__ __forceinline__ int swz(int row, int chunk) {
    return row * 256 + ((chunk ^ (row & 7)) << 4);
}

// transpose-region byte offset: [row 0..63][col 0..127] bf16, 256B/row.
static __device__ __forceinline__ int tswz(int row, int col) {
    int chunk = (col >> 3) ^ ((row >> 1) & 6);
    return row * 256 + (chunk << 4) + ((col & 7) << 1);
}

// LDS-only barrier: does NOT drain vmcnt -> global stores stay in flight.
static __device__ __forceinline__ void bar_lds() {
    asm volatile("s_waitcnt lgkmcnt(0)" ::: "memory");
    __builtin_amdgcn_s_barrier();
    asm volatile("" ::: "memory");
}

// within-wave LDS fence: drain DS ops + block compiler (TBAA) reordering
static __device__ __forceinline__ void fence_lds() {
    asm volatile("s_waitcnt lgkmcnt(0)" ::: "memory");
}

//=============== prep kernel: weights -> bf16 LDS-layout images in ws ===========
__global__ __launch_bounds__(256) void moe_prep(
    const float* __restrict__ gate_w, const float* __restrict__ w1,
    const float* __restrict__ w2, char* __restrict__ ws)
{
    const int t = threadIdx.x;
    const int b = blockIdx.x;
    if (b < 4) {
        // w1t image: p = e*16+i rows, swizzled; block b covers cc = 2b, 2b+1
        const int p = t & 127, ch = t >> 7;
        const float* w1b = w1 + (p >> 4) * 2048 + (p & 15);   // w1[e][c][i]
        #pragma unroll
        for (int q = 0; q < 2; ++q) {
            int cc = 2 * b + q;
            short8 v;
            #pragma unroll
            for (int j = 0; j < 8; ++j)
                v[j] = (short)f2bf(w1b[(ch * 64 + cc * 8 + j) * 16]);
            *(short8*)(ws + swz(p, ch * 8 + cc)) = v;
        }
        // gfr image: lane l holds 4 short8 A-fragments of gate_w (col<8 rows)
        if (b == 0 && t < 64) {
            const int col = t & 15, ak = t >> 4;
            #pragma unroll
            for (int ks = 0; ks < 4; ++ks) {
                short8 v;
                #pragma unroll
                for (int j = 0; j < 8; ++j) {
                    float f = (col < 8) ? gate_w[(32 * ks + 8 * ak + j) * 8 + col] : 0.0f;
                    v[j] = (short)f2bf(f);
                }
                *(short8*)(ws + WS_GFR + t * 64 + ks * 16) = v;
            }
        }
    } else {
        // w2t image: w2t[(e,c)][i] bf16, chunk' = (rc*2+half) ^ ((c>>2)&3)
        const int e2 = t >> 5, colq = (t & 31) * 4;
        const int cc = b - 4;
        const int c = colq + cc;
        const float* w2b = w2 + e2 * 2048 + c;   // w2[e][i][c]
        unsigned pkc[8];
        #pragma unroll
        for (int q = 0; q < 8; ++q) pkc[q] = 0u;
        #pragma unroll
        for (int i = 0; i < 16; ++i)
            pkc[i >> 1] |= (unsigned)f2bf(w2b[i * 128]) << ((i & 1) * 16);
        const int rc = e2 * 128 + c;
        const int a = (c >> 2) & 3;
        *(uint4*)(ws + WS_W2T + (((rc * 2 + 0) ^ a) << 4)) =
            make_uint4(pkc[0], pkc[1], pkc[2], pkc[3]);
        *(uint4*)(ws + WS_W2T + (((rc * 2 + 1) ^ a) << 4)) =
            make_uint4(pkc[4], pkc[5], pkc[6], pkc[7]);
    }
}

//=============================== main kernel ====================================
__global__ __launch_bounds__(256, 2) void moe_fused(
    const float* __restrict__ x, const float* __restrict__ ln_g,
    const float* __restrict__ ln_b, const float* __restrict__ gate_b,
    const char* __restrict__ wsw, float* __restrict__ out)
{
    // 66 KB: 2 blocks/CU (VGPR cap 256 -- no spills)
    __shared__ __align__(16) char smem[67584];
    char* pXY = smem;                      // 16KB: xn (bf16), y overwrites per expert
    char* pW  = smem + 16384;              // 32KB: w1t (live all of P4), then agg f32
    char* pTR = smem + 49152;              // 16KB: bf16 transpose buffer (out2 tiles)
    float* pRW = (float*)(smem + 65536);   // 2KB: routing weights [64][8] f32

    const int t = threadIdx.x;
    const int l = t & 63;
    const int w = t >> 6;
    const int tok0 = blockIdx.x * 64;

    const int colq = (t & 31) * 4;   // P0-layout columns
    const int rsub = t >> 5;         // P0-layout row sub-index

    const int rb = w * 16;           // wave's 16 token rows
    const int col = l & 15;          // MFMA n / lane col (token index in tiles)
    const int ak = l >> 4;           // MFMA k-subgroup / token 4-row group
    const int arow = rb + col;

    //---------------- P0: global loads + staging ----------------
    float4 xv[8];                    // x tile, held in regs to the end
    {
        const float* xb = x + (size_t)tok0 * 128;
        #pragma unroll
        for (int s = 0; s < 8; ++s)
            xv[s] = *(const float4*)(xb + s * 1024 + t * 4);
    }
    float4 g4 = *(const float4*)(ln_g + colq);
    float4 b4 = *(const float4*)(ln_b + colq);

    // w1t image -> pW: linear 32KB block copy (layout already final)
    #pragma unroll
    for (int k = 0; k < 8; ++k)
        *(uint4*)(pW + t * 16 + k * 4096) = *(const uint4*)(wsw + t * 16 + k * 4096);

    // gate fragments from image (4KB, L1-broadcast across waves)
    short8 gfr[4];
    #pragma unroll
    for (int ks = 0; ks < 4; ++ks)
        gfr[ks] = *(const short8*)(wsw + WS_GFR + l * 64 + ks * 16);
    float4 gb4 = *(const float4*)(gate_b + (ak & 1) * 4);

    //---------------- LN in registers, xn -> LDS ----------------
    #pragma unroll
    for (int s = 0; s < 8; ++s) {
        float4 v = xv[s];
        float sm = v.x + v.y + v.z + v.w;
        float sq = v.x*v.x + v.y*v.y + v.z*v.z + v.w*v.w;
        #pragma unroll
        for (int m = 1; m < 32; m <<= 1) {
            sm += __shfl_xor(sm, m, 64);
            sq += __shfl_xor(sq, m, 64);
        }
        float mu = sm * (1.0f / 128.0f);
        float var = sq * (1.0f / 128.0f) - mu * mu;
        float rs = rsqrtf(var + 1e-5f);
        float n0 = (v.x - mu) * rs * g4.x + b4.x;
        float n1 = (v.y - mu) * rs * g4.y + b4.y;
        float n2 = (v.z - mu) * rs * g4.z + b4.z;
        float n3 = (v.w - mu) * rs * g4.w + b4.w;
        unsigned lo = (unsigned)f2bf(n0) | ((unsigned)f2bf(n1) << 16);
        unsigned hi = (unsigned)f2bf(n2) | ((unsigned)f2bf(n3) << 16);
        unsigned long long dvv = (unsigned long long)lo | ((unsigned long long)hi << 32);
        int row = s * 8 + rsub;
        *(unsigned long long*)(pXY + swz(row, colq >> 3) + (colq & 7) * 2) = dvv;
    }

    bar_lds();   // bar1: xn + w1t ready

    const f32x4 zero4 = {0.f, 0.f, 0.f, 0.f};
    const short8 zfrag = {0, 0, 0, 0, 0, 0, 0, 0};

    // xn fragments (lane col = token within wave tile, k = c)
    short8 afr[4];
    #pragma unroll
    for (int ks = 0; ks < 4; ++ks)
        afr[ks] = *(const short8*)(pXY + swz(arow, ks * 4 + ak));

    //---------------- gating (swapped): D[e][token] ----------------
    f32x4 accg = zero4;
    #pragma unroll
    for (int ks = 0; ks < 4; ++ks)
        accg = __builtin_amdgcn_mfma_f32_16x16x32_bf16(gfr[ks], afr[ks], accg, 0, 0, 0);

    const size_t trow = (size_t)(tok0 + arow);
    {
        // lane holds logits for token trow, experts e = ak*4 + r (valid ak<2)
        float lg0 = accg[0] + gb4.x;
        float lg1 = accg[1] + gb4.y;
        float lg2 = accg[2] + gb4.z;
        float lg3 = accg[3] + gb4.w;
        if (ak < 2) {
            f32x4 lgv = {lg0, lg1, lg2, lg3};
            *(f32x4*)(out + O1_OFF + trow * 8 + ak * 4) = lgv;
        }
        float mx = fmaxf(fmaxf(lg0, lg1), fmaxf(lg2, lg3));
        mx = fmaxf(mx, __shfl_xor(mx, 16, 64));
        float ex0 = __expf(lg0 - mx), ex1 = __expf(lg1 - mx);
        float ex2 = __expf(lg2 - mx), ex3 = __expf(lg3 - mx);
        float sm = ex0 + ex1 + ex2 + ex3;
        sm += __shfl_xor(sm, 16, 64);
        float inv = 1.0f / sm;
        if (ak < 2) {
            f32x4 pv = {ex0 * inv, ex1 * inv, ex2 * inv, ex3 * inv};
            *(f32x4*)(pRW + arow * 8 + ak * 4) = pv;
        }
    }

    fence_lds();   // pRW writes visible to own wave's reads below

    //---------------- P4 (fused stage-B): per expert: y_e -> GEMM -> stores -----
    f32x4 agg[8];
    #pragma unroll
    for (int nt = 0; nt < 8; ++nt) agg[nt] = zero4;

    #pragma unroll
    for (int e = 0; e < 8; ++e) {
        // ---- stage-B slice: y_e = gelu(xn @ w1[e]) for this wave's tokens ----
        f32x4 accb = zero4;
        #pragma unroll
        for (int ks = 0; ks < 4; ++ks) {
            short8 wfr = *(const short8*)(pW + swz(e * 16 + col, ks * 4 + ak));
            accb = __builtin_amdgcn_mfma_f32_16x16x32_bf16(wfr, afr[ks], accb, 0, 0, 0);
        }
        {
            float y0 = accb[0], y1 = accb[1], y2 = accb[2], y3 = accb[3];
            y0 = 0.5f * y0 * (1.0f + erff(y0 * 0.70710678118654752f));
            y1 = 0.5f * y1 * (1.0f + erff(y1 * 0.70710678118654752f));
            y2 = 0.5f * y2 * (1.0f + erff(y2 * 0.70710678118654752f));
            y3 = 0.5f * y3 * (1.0f + erff(y3 * 0.70710678118654752f));
            unsigned lo = (unsigned)f2bf(y0) | ((unsigned)f2bf(y1) << 16);
            unsigned hi = (unsigned)f2bf(y2) | ((unsigned)f2bf(y3) << 16);
            unsigned long long dv = (unsigned long long)lo | ((unsigned long long)hi << 32);
            *(unsigned long long*)(pXY + swz(arow, e * 2 + (ak >> 1)) + (ak & 1) * 8) = dv;
        }
        fence_lds();   // own-row y write -> own-row y read (wave-private)

        // ---- expert GEMM: w2 B-frags straight from ws image (L1/L2-hot) ----
        float rwe[4];
        #pragma unroll
        for (int r = 0; r < 4; ++r)
            rwe[r] = pRW[(rb + ak * 4 + r) * 8 + e];
        short8 alo = *(const short8*)(pXY + swz(arow, 2 * e + (ak & 1)));
        short8 af = (ak < 2) ? alo : zfrag;    // K=16 padded to 32
        f32x4 ot[8];
        #pragma unroll
        for (int nt = 0; nt < 8; ++nt) {
            int c = nt * 16 + col;
            int rc = e * 128 + c;
            int a = (c >> 2) & 3;
            short8 blo = *(const short8*)(wsw + WS_W2T + (((rc * 2 + (ak & 1)) ^ a) << 4));
            short8 bf = (ak < 2) ? blo : zfrag;
            ot[nt] = __builtin_amdgcn_mfma_f32_16x16x32_bf16(af, bf, zero4, 0, 0, 0);
            #pragma unroll
            for (int r = 0; r < 4; ++r)
                agg[nt][r] += rwe[r] * ot[nt][r];
        }
        // MFMA-layout -> bf16 transpose slice (wave-private rows)
        #pragma unroll
        for (int nt = 0; nt < 8; ++nt)
            #pragma unroll
            for (int r = 0; r < 4; ++r)
                *(unsigned short*)(pTR + tswz(rb + ak * 4 + r, nt * 16 + col)) = f2bf(ot[nt][r]);
        fence_lds();   // drain DS writes + block compiler reordering (TBAA)
        // read back row-major: 2 full token-expert rows per instruction
        #pragma unroll
        for (int i2 = 0; i2 < 8; ++i2) {
            int row = rb + i2 * 2 + (l >> 5);
            int c0 = (l & 31) * 4;
            unsigned long long raw = *(const unsigned long long*)(pTR + tswz(row, c0));
            unsigned lo = (unsigned)raw, hi = (unsigned)(raw >> 32);
            f32x4 v;
            v[0] = __builtin_bit_cast(float, lo << 16);
            v[1] = __builtin_bit_cast(float, lo & 0xffff0000u);
            v[2] = __builtin_bit_cast(float, hi << 16);
            v[3] = __builtin_bit_cast(float, hi & 0xffff0000u);
            __builtin_nontemporal_store(v,
                (f32x4*)(out + O2_OFF + (size_t)(tok0 + row) * 1024 + e * 128 + c0));
        }
        asm volatile("" ::: "memory");   // keep next expert's writes after these reads
    }

    bar_lds();   // bar4: all waves' w1t reads done -> pW reusable for agg (f32)

    //---------------- epilogue: f32 agg through pW (R0-verified scheme) ----------
    #pragma unroll
    for (int nt = 0; nt < 8; ++nt) {
        int c = nt * 16 + col;
        #pragma unroll
        for (int r = 0; r < 4; ++r) {
            int row = rb + ak * 4 + r;
            *(float*)(pW + row * 512 + ((c << 2) ^ ((row & 4) << 2))) = agg[nt][r];
        }
    }

    bar_lds();   // bar5: agg tile ready in P0 layout

    #pragma unroll
    for (int s = 0; s < 8; ++s) {
        int row = s * 8 + rsub;
        f32x4 a4 = *(const f32x4*)(pW + row * 512 + ((colq << 2) ^ ((row & 4) << 2)));
        f32x4 o;
        o[0] = xv[s].x + a4[0];
        o[1] = xv[s].y + a4[1];
        o[2] = xv[s].z + a4[2];
        o[3] = xv[s].w + a4[3];
        __builtin_nontemporal_store(o,
            (f32x4*)(out + (size_t)(tok0 + row) * 128 + colq));
    }
}

extern "C" void kernel_launch(void* const* d_in, const int* in_sizes, int n_in,
                              void* d_out, int out_size, void* d_ws, size_t ws_size,
                              hipStream_t stream) {
    const float* x      = (const float*)d_in[0];
    const float* ln_g   = (const float*)d_in[1];
    const float* ln_b   = (const float*)d_in[2];
    const float* gate_w = (const float*)d_in[3];
    const float* gate_b = (const float*)d_in[4];
    const float* w1     = (const float*)d_in[5];
    const float* w2     = (const float*)d_in[6];
    float* out = (float*)d_out;
    char* ws = (char*)d_ws;
    (void)in_sizes; (void)n_in; (void)out_size; (void)ws_size;
    moe_prep<<<dim3(8), dim3(256), 0, stream>>>(gate_w, w1, w2, ws);
    moe_fused<<<dim3(1024), dim3(256), 0, stream>>>(x, ln_g, ln_b, gate_b, ws, out);
}

// Round 13
// 81.689 us; speedup vs baseline: 1.7788x; 1.7788x over previous
//
#include <hip/hip_runtime.h>
#include <math.h>

// Problem: B=8, T=8192, D=128, E=8, I=16.  BT = 65536 tokens.
// Outputs concatenated f32: out0 [BT,128] | out1 [BT,8] | out2 [BT,8,128]
// R13: R9 (78.4 us) + (a) amdgpu_waves_per_eu(2,2) pin -- prevents the
// allocator's 128-VGPR/spill heuristic (R5/R10/R11/R12 failure mode);
// (b) w2t staged via registers from the packed image (R4 pattern): loads
// issue in P0 (latency hidden under LN/gating/stage-B), LDS writes after
// bar2 -- deletes the exposed bar2->bar3 global-load window.
#define O1_OFF 8388608
#define O2_OFF 8912896

// d_ws layout: [0,32768) w1t image | [32768,65536) w2t image | [65536,69632) gfr image
#define WS_W2T 32768
#define WS_GFR 65536

typedef __attribute__((ext_vector_type(8))) short short8;
typedef __attribute__((ext_vector_type(4))) float f32x4;

static __device__ __forceinline__ unsigned short f2bf(float f) {
    unsigned u = __builtin_bit_cast(unsigned, f);
    u = (u + 0x7fffu + ((u >> 16) & 1u)) >> 16;   // RNE
    return (unsigned short)u;
}

// swizzled byte offset inside a [rows][16 x 16B-chunks] LDS region (weights/xn/y)
static __device__ __forceinline__ int swz(int row, int chunk) {
    return row * 256 + ((chunk ^ (row & 7)) << 4);
}

// transpose-region byte offset: [row 0..63][col 0..127] bf16, 256B/row.
static __device__ __forceinline__ int tswz(int row, int col) {
    int chunk = (col >> 3) ^ ((row >> 1) & 6);
    return row * 256 + (chunk << 4) + ((col & 7) << 1);
}

// LDS-only barrier: does NOT drain vmcnt -> global stores stay in flight.
static __device__ __forceinline__ void bar_lds() {
    asm volatile("s_waitcnt lgkmcnt(0)" ::: "memory");
    __builtin_amdgcn_s_barrier();
    asm volatile("" ::: "memory");
}

// within-wave LDS fence: drain DS ops + block compiler (TBAA) reordering
static __device__ __forceinline__ void fence_lds() {
    asm volatile("s_waitcnt lgkmcnt(0)" ::: "memory");
}

//=============== prep kernel: weights -> bf16 LDS-layout images in ws ===========
__global__ __launch_bounds__(256) void moe_prep(
    const float* __restrict__ gate_w, const float* __restrict__ w1,
    const float* __restrict__ w2, char* __restrict__ ws)
{
    const int t = threadIdx.x;
    const int b = blockIdx.x;
    if (b < 4) {
        // w1t image: p = e*16+i rows, swizzled; block b covers cc = 2b, 2b+1
        const int p = t & 127, ch = t >> 7;
        const float* w1b = w1 + (p >> 4) * 2048 + (p & 15);   // w1[e][c][i]
        #pragma unroll
        for (int q = 0; q < 2; ++q) {
            int cc = 2 * b + q;
            short8 v;
            #pragma unroll
            for (int j = 0; j < 8; ++j)
                v[j] = (short)f2bf(w1b[(ch * 64 + cc * 8 + j) * 16]);
            *(short8*)(ws + swz(p, ch * 8 + cc)) = v;
        }
        // gfr image: lane l holds 4 short8 A-fragments of gate_w (col<8 rows)
        if (b == 0 && t < 64) {
            const int col = t & 15, ak = t >> 4;
            #pragma unroll
            for (int ks = 0; ks < 4; ++ks) {
                short8 v;
                #pragma unroll
                for (int j = 0; j < 8; ++j) {
                    float f = (col < 8) ? gate_w[(32 * ks + 8 * ak + j) * 8 + col] : 0.0f;
                    v[j] = (short)f2bf(f);
                }
                *(short8*)(ws + WS_GFR + t * 64 + ks * 16) = v;
            }
        }
    } else {
        // w2t image: w2t[(e,c)][i] bf16, chunk' = (rc*2+half) ^ ((c>>2)&3)
        const int e2 = t >> 5, colq = (t & 31) * 4;
        const int cc = b - 4;
        const int c = colq + cc;
        const float* w2b = w2 + e2 * 2048 + c;   // w2[e][i][c]
        unsigned pkc[8];
        #pragma unroll
        for (int q = 0; q < 8; ++q) pkc[q] = 0u;
        #pragma unroll
        for (int i = 0; i < 16; ++i)
            pkc[i >> 1] |= (unsigned)f2bf(w2b[i * 128]) << ((i & 1) * 16);
        const int rc = e2 * 128 + c;
        const int a = (c >> 2) & 3;
        *(uint4*)(ws + WS_W2T + (((rc * 2 + 0) ^ a) << 4)) =
            make_uint4(pkc[0], pkc[1], pkc[2], pkc[3]);
        *(uint4*)(ws + WS_W2T + (((rc * 2 + 1) ^ a) << 4)) =
            make_uint4(pkc[4], pkc[5], pkc[6], pkc[7]);
    }
}

//=============================== main kernel ====================================
__global__ __launch_bounds__(256, 2)
__attribute__((amdgpu_waves_per_eu(2, 2)))
void moe_fused(
    const float* __restrict__ x, const float* __restrict__ ln_g,
    const float* __restrict__ ln_b, const float* __restrict__ gate_b,
    const char* __restrict__ wsw, float* __restrict__ out)
{
    // 66 KB: 2 blocks/CU (VGPR budget pinned to 2 waves/EU -> 256)
    __shared__ __align__(16) char smem[67584];
    char* pXY = smem;                      // 16KB: xn (bf16), then y (bf16)
    char* pW  = smem + 16384;              // 32KB: w1t, then w2t, then agg f32
    char* pTR = smem + 49152;              // 16KB: bf16 transpose buffer (out2 tiles)
    float* pRW = (float*)(smem + 65536);   // 2KB: routing weights [64][8] f32

    const int t = threadIdx.x;
    const int l = t & 63;
    const int w = t >> 6;
    const int tok0 = blockIdx.x * 64;

    const int colq = (t & 31) * 4;   // P0-layout columns
    const int rsub = t >> 5;         // P0-layout row sub-index

    const int rb = w * 16;           // wave's 16 token rows
    const int col = l & 15;          // MFMA n / lane col (token index in tiles)
    const int ak = l >> 4;           // MFMA k-subgroup / token 4-row group
    const int arow = rb + col;

    //---------------- P0: global loads + staging ----------------
    float4 xv[8];                    // x tile, held in regs to the end
    {
        const float* xb = x + (size_t)tok0 * 128;
        #pragma unroll
        for (int s = 0; s < 8; ++s)
            xv[s] = *(const float4*)(xb + s * 1024 + t * 4);
    }
    float4 g4 = *(const float4*)(ln_g + colq);
    float4 b4 = *(const float4*)(ln_b + colq);

    // w1t image -> pW: linear 32KB block copy (layout already final)
    #pragma unroll
    for (int k = 0; k < 8; ++k)
        *(uint4*)(pW + t * 16 + k * 4096) = *(const uint4*)(wsw + t * 16 + k * 4096);

    // w2t image -> registers (R4 pattern): loads issue now, LDS writes after bar2
    uint4 w2r[8];
    #pragma unroll
    for (int k = 0; k < 8; ++k)
        w2r[k] = *(const uint4*)(wsw + WS_W2T + t * 16 + k * 4096);

    // gate fragments from image (4KB, L1-broadcast across waves)
    short8 gfr[4];
    #pragma unroll
    for (int ks = 0; ks < 4; ++ks)
        gfr[ks] = *(const short8*)(wsw + WS_GFR + l * 64 + ks * 16);
    float4 gb4 = *(const float4*)(gate_b + (ak & 1) * 4);

    //---------------- LN in registers, xn -> LDS ----------------
    #pragma unroll
    for (int s = 0; s < 8; ++s) {
        float4 v = xv[s];
        float sm = v.x + v.y + v.z + v.w;
        float sq = v.x*v.x + v.y*v.y + v.z*v.z + v.w*v.w;
        #pragma unroll
        for (int m = 1; m < 32; m <<= 1) {
            sm += __shfl_xor(sm, m, 64);
            sq += __shfl_xor(sq, m, 64);
        }
        float mu = sm * (1.0f / 128.0f);
        float var = sq * (1.0f / 128.0f) - mu * mu;
        float rs = rsqrtf(var + 1e-5f);
        float n0 = (v.x - mu) * rs * g4.x + b4.x;
        float n1 = (v.y - mu) * rs * g4.y + b4.y;
        float n2 = (v.z - mu) * rs * g4.z + b4.z;
        float n3 = (v.w - mu) * rs * g4.w + b4.w;
        unsigned lo = (unsigned)f2bf(n0) | ((unsigned)f2bf(n1) << 16);
        unsigned hi = (unsigned)f2bf(n2) | ((unsigned)f2bf(n3) << 16);
        unsigned long long dvv = (unsigned long long)lo | ((unsigned long long)hi << 32);
        int row = s * 8 + rsub;
        *(unsigned long long*)(pXY + swz(row, colq >> 3) + (colq & 7) * 2) = dvv;
    }

    bar_lds();   // bar1: xn + w1t ready

    const f32x4 zero4 = {0.f, 0.f, 0.f, 0.f};
    const short8 zfrag = {0, 0, 0, 0, 0, 0, 0, 0};

    // xn fragments (lane col = token within wave tile, k = c)
    short8 afr[4];
    #pragma unroll
    for (int ks = 0; ks < 4; ++ks)
        afr[ks] = *(const short8*)(pXY + swz(arow, ks * 4 + ak));

    //---------------- gating (swapped): D[e][token] ----------------
    f32x4 accg = zero4;
    #pragma unroll
    for (int ks = 0; ks < 4; ++ks)
        accg = __builtin_amdgcn_mfma_f32_16x16x32_bf16(gfr[ks], afr[ks], accg, 0, 0, 0);

    const size_t trow = (size_t)(tok0 + arow);
    {
        // lane holds logits for token trow, experts e = ak*4 + r (valid ak<2)
        float lg0 = accg[0] + gb4.x;
        float lg1 = accg[1] + gb4.y;
        float lg2 = accg[2] + gb4.z;
        float lg3 = accg[3] + gb4.w;
        if (ak < 2) {
            f32x4 lgv = {lg0, lg1, lg2, lg3};
            *(f32x4*)(out + O1_OFF + trow * 8 + ak * 4) = lgv;
        }
        float mx = fmaxf(fmaxf(lg0, lg1), fmaxf(lg2, lg3));
        mx = fmaxf(mx, __shfl_xor(mx, 16, 64));
        float ex0 = __expf(lg0 - mx), ex1 = __expf(lg1 - mx);
        float ex2 = __expf(lg2 - mx), ex3 = __expf(lg3 - mx);
        float sm = ex0 + ex1 + ex2 + ex3;
        sm += __shfl_xor(sm, 16, 64);
        float inv = 1.0f / sm;
        if (ak < 2) {
            f32x4 pv = {ex0 * inv, ex1 * inv, ex2 * inv, ex3 * inv};
            *(f32x4*)(pRW + arow * 8 + ak * 4) = pv;
        }
    }

    //---------------- stage B (swapped): y^T per token in-lane ----------------
    f32x4 accb[8];
    #pragma unroll
    for (int nt = 0; nt < 8; ++nt) accb[nt] = zero4;
    #pragma unroll
    for (int ks = 0; ks < 4; ++ks)
        #pragma unroll
        for (int nt = 0; nt < 8; ++nt) {
            short8 wfr = *(const short8*)(pW + swz(nt * 16 + col, ks * 4 + ak));
            accb[nt] = __builtin_amdgcn_mfma_f32_16x16x32_bf16(wfr, afr[ks], accb[nt], 0, 0, 0);
        }

    // exact-erf GELU; lane holds token arow, ei = nt*16 + ak*4 + r -> 8B packed write
    #pragma unroll
    for (int nt = 0; nt < 8; ++nt) {
        float y0 = accb[nt][0], y1 = accb[nt][1], y2 = accb[nt][2], y3 = accb[nt][3];
        y0 = 0.5f * y0 * (1.0f + erff(y0 * 0.70710678118654752f));
        y1 = 0.5f * y1 * (1.0f + erff(y1 * 0.70710678118654752f));
        y2 = 0.5f * y2 * (1.0f + erff(y2 * 0.70710678118654752f));
        y3 = 0.5f * y3 * (1.0f + erff(y3 * 0.70710678118654752f));
        unsigned lo = (unsigned)f2bf(y0) | ((unsigned)f2bf(y1) << 16);
        unsigned hi = (unsigned)f2bf(y2) | ((unsigned)f2bf(y3) << 16);
        unsigned long long dv = (unsigned long long)lo | ((unsigned long long)hi << 32);
        *(unsigned long long*)(pXY + swz(arow, nt * 2 + (ak >> 1)) + (ak & 1) * 8) = dv;
    }

    bar_lds();   // bar2: all stage-B w1t reads done -> w1t region reusable

    // staged w2 regs -> pW: 8 linear b128 writes (no global latency here)
    #pragma unroll
    for (int k = 0; k < 8; ++k)
        *(uint4*)(pW + t * 16 + k * 4096) = w2r[k];

    bar_lds();   // bar3: w2t + y + pRW ready

    //---------------- P4: per-expert GEMM -> LDS transpose -> full-line stores ---
    f32x4 agg[8];
    #pragma unroll
    for (int nt = 0; nt < 8; ++nt) agg[nt] = zero4;

    #pragma unroll
    for (int e = 0; e < 8; ++e) {
        float rwe[4];
        #pragma unroll
        for (int r = 0; r < 4; ++r)
            rwe[r] = pRW[(rb + ak * 4 + r) * 8 + e];
        short8 alo = *(const short8*)(pXY + swz(arow, 2 * e + (ak & 1)));
        short8 af = (ak < 2) ? alo : zfrag;    // K=16 padded to 32
        f32x4 ot[8];
        #pragma unroll
        for (int nt = 0; nt < 8; ++nt) {
            int c = nt * 16 + col;
            int rc = e * 128 + c;
            int a = (c >> 2) & 3;
            short8 blo = *(const short8*)(pW + (((rc * 2 + (ak & 1)) ^ a) << 4));
            short8 bf = (ak < 2) ? blo : zfrag;
            ot[nt] = __builtin_amdgcn_mfma_f32_16x16x32_bf16(af, bf, zero4, 0, 0, 0);
            #pragma unroll
            for (int r = 0; r < 4; ++r)
                agg[nt][r] += rwe[r] * ot[nt][r];
        }
        // MFMA-layout -> bf16 transpose slice (wave-private rows)
        #pragma unroll
        for (int nt = 0; nt < 8; ++nt)
            #pragma unroll
            for (int r = 0; r < 4; ++r)
                *(unsigned short*)(pTR + tswz(rb + ak * 4 + r, nt * 16 + col)) = f2bf(ot[nt][r]);
        fence_lds();   // drain DS writes + block compiler reordering (TBAA)
        // read back row-major: 2 full token-expert rows per instruction
        #pragma unroll
        for (int i2 = 0; i2 < 8; ++i2) {
            int row = rb + i2 * 2 + (l >> 5);
            int c0 = (l & 31) * 4;
            unsigned long long raw = *(const unsigned long long*)(pTR + tswz(row, c0));
            unsigned lo = (unsigned)raw, hi = (unsigned)(raw >> 32);
            f32x4 v;
            v[0] = __builtin_bit_cast(float, lo << 16);
            v[1] = __builtin_bit_cast(float, lo & 0xffff0000u);
            v[2] = __builtin_bit_cast(float, hi << 16);
            v[3] = __builtin_bit_cast(float, hi & 0xffff0000u);
            __builtin_nontemporal_store(v,
                (f32x4*)(out + O2_OFF + (size_t)(tok0 + row) * 1024 + e * 128 + c0));
        }
        asm volatile("" ::: "memory");   // keep next expert's writes after these reads
    }

    bar_lds();   // bar4: all waves' w2t reads done -> pW reusable for agg (f32)

    //---------------- epilogue: f32 agg through pW (R0-verified scheme) ----------
    #pragma unroll
    for (int nt = 0; nt < 8; ++nt) {
        int c = nt * 16 + col;
        #pragma unroll
        for (int r = 0; r < 4; ++r) {
            int row = rb + ak * 4 + r;
            *(float*)(pW + row * 512 + ((c << 2) ^ ((row & 4) << 2))) = agg[nt][r];
        }
    }

    bar_lds();   // bar5: agg tile ready in P0 layout

    #pragma unroll
    for (int s = 0; s < 8; ++s) {
        int row = s * 8 + rsub;
        f32x4 a4 = *(const f32x4*)(pW + row * 512 + ((colq << 2) ^ ((row & 4) << 2)));
        f32x4 o;
        o[0] = xv[s].x + a4[0];
        o[1] = xv[s].y + a4[1];
        o[2] = xv[s].z + a4[2];
        o[3] = xv[s].w + a4[3];
        __builtin_nontemporal_store(o,
            (f32x4*)(out + (size_t)(tok0 + row) * 128 + colq));
    }
}

extern "C" void kernel_launch(void* const* d_in, const int* in_sizes, int n_in,
                              void* d_out, int out_size, void* d_ws, size_t ws_size,
                              hipStream_t stream) {
    const float* x      = (const float*)d_in[0];
    const float* ln_g   = (const float*)d_in[1];
    const float* ln_b   = (const float*)d_in[2];
    const float* gate_w = (const float*)d_in[3];
    const float* gate_b = (const float*)d_in[4];
    const float* w1     = (const float*)d_in[5];
    const float* w2     = (const float*)d_in[6];
    float* out = (float*)d_out;
    char* ws = (char*)d_ws;
    (void)in_sizes; (void)n_in; (void)out_size; (void)ws_size;
    moe_prep<<<dim3(8), dim3(256), 0, stream>>>(gate_w, w1, w2, ws);
    moe_fused<<<dim3(1024), dim3(256), 0, stream>>>(x, ln_g, ln_b, gate_b, ws, out);
}